// Round 2
// baseline (203.709 us; speedup 1.0000x reference)
//
#include <hip/hip_runtime.h>

// Problem constants (fixed by setup_inputs)
#define Bdim 32
#define Ndim 64
#define Tdim 40
#define Adim 6
#define Zdim 64
#define Cdim 3
#define BNT   (Bdim * Ndim * Tdim)   // 81920
#define ROWS  (BNT * Adim)           // 491520 rows of 64 floats (= out elements)

// logits[b,n,t,a] = dot(df[b,n,t,a,:], z[b,n,:]) + u[b,n,t,a] - feas_mean_a(u)
// The frenet/projection contribution is constant over (t,a) and cancels exactly
// in (u - u_mean), so map_polylines/idx/pts are dead inputs.

// ---------------- Kernel B: dot products, writes out = dot ----------------
// One wave = 4 rows. lane group g = lane>>4 handles row wave*4+g,
// elements c = 4*(lane&15)..+3. df float4 index = wave*256 + lane*4 (contiguous).
// Reduction over the 16-lane group: 4 DPP row_shr adds (pure VALU, no DS pipe).

template <int CTRL>
__device__ __forceinline__ float dpp_shr_add(float v) {
    int s = __builtin_amdgcn_update_dpp(0, __float_as_int(v), CTRL, 0xF, 0xF, true);
    return v + __int_as_float(s);
}

__global__ __launch_bounds__(256) void mpd_dot_kernel(
    const float* __restrict__ df,   // (B,N,T,A,Z)
    const float* __restrict__ z,    // (B,N,Z)
    float*       __restrict__ out)  // (B,N,T,A)
{
    const int tid  = blockIdx.x * blockDim.x + threadIdx.x;
    const int wave = tid >> 6;
    const int lane = tid & 63;

    const float4 d4 = *reinterpret_cast<const float4*>(df + (size_t)wave * 256 + lane * 4);
    const int bn = wave / 60;  // = (wave*4)/240; 240 rows per (b,n), 4 | 240
    const float4 z4 = *reinterpret_cast<const float4*>(z + bn * Zdim + (lane & 15) * 4);

    float p = d4.x * z4.x + d4.y * z4.y + d4.z * z4.z + d4.w * z4.w;
    p = dpp_shr_add<0x111>(p);  // row_shr:1
    p = dpp_shr_add<0x112>(p);  // row_shr:2
    p = dpp_shr_add<0x114>(p);  // row_shr:4
    p = dpp_shr_add<0x118>(p);  // row_shr:8  -> lane 15 of each 16-group = row sum

    if ((lane & 15) == 15)
        out[wave * 4 + (lane >> 4)] = p;
}

// ---------------- Kernel A: epilogue, out += u - feas_mean(u) ----------------
// One thread per (b,n,t). ctx (18 floats/thread) staged via coalesced float4
// loads into LDS; feas/out accessed directly (hardware-coalesced).

__global__ __launch_bounds__(256) void mpd_epi_kernel(
    const float* __restrict__ ctx,   // (B,N,T,A,C)
    const int*   __restrict__ feas,  // (B,N,T,A)
    const float* __restrict__ w,     // (C,)
    const float* __restrict__ b0,    // (1,)
    float*       __restrict__ out)   // (B,N,T,A), already holds dot
{
    __shared__ float ctxL[256 * Adim * Cdim];  // 18 KiB
    const int tloc = threadIdx.x;
    const int gid  = blockIdx.x * 256 + tloc;

    const float* cbase = ctx + (size_t)blockIdx.x * (256 * Adim * Cdim);
    for (int i = tloc * 4; i < 256 * Adim * Cdim; i += 256 * 4) {
        *reinterpret_cast<float4*>(&ctxL[i]) =
            *reinterpret_cast<const float4*>(cbase + i);
    }
    __syncthreads();

    const float w0 = w[0], w1 = w[1], w2 = w[2], bb = b0[0];
    const int* fp = feas + gid * Adim;

    float u[Adim], fv[Adim];
    bool any = false;
#pragma unroll
    for (int a = 0; a < Adim; ++a) {
        const float* c = &ctxL[tloc * (Adim * Cdim) + a * Cdim];
        u[a] = c[0] * w0 + c[1] * w1 + c[2] * w2 + bb;
        const bool f = (fp[a] != 0);
        fv[a] = f ? 1.0f : 0.0f;
        any = any || f;
    }

    float us = 0.0f, fs = 0.0f;
#pragma unroll
    for (int a = 0; a < Adim; ++a) {
        const float f = any ? fv[a] : 1.0f;
        us += u[a] * f;
        fs += f;
    }
    const float mean = us / fmaxf(fs, 1e-6f);

    float* op = out + gid * Adim;
#pragma unroll
    for (int a = 0; a < Adim; ++a)
        op[a] = op[a] + (u[a] - mean);
}

extern "C" void kernel_launch(void* const* d_in, const int* in_sizes, int n_in,
                              void* d_out, int out_size, void* d_ws, size_t ws_size,
                              hipStream_t stream) {
    // Inputs: map_polylines(0), idx(1), pts(2), z(3), decision_features(4),
    //         ctx_features(5), feasible_actions(6), u_ctx_w(7), u_ctx_b(8)
    const float* z    = (const float*)d_in[3];
    const float* df   = (const float*)d_in[4];
    const float* ctx  = (const float*)d_in[5];
    const int*   feas = (const int*)  d_in[6];
    const float* w    = (const float*)d_in[7];
    const float* b0   = (const float*)d_in[8];
    float* out = (float*)d_out;

    // Kernel B: 122880 waves (4 rows each), 256-thread blocks -> 30720 blocks
    const int gridB = (ROWS / 4) * 64 / 256;
    mpd_dot_kernel<<<gridB, 256, 0, stream>>>(df, z, out);

    // Kernel A: one thread per (b,n,t) -> 81920 threads -> 320 blocks
    const int gridA = BNT / 256;
    mpd_epi_kernel<<<gridA, 256, 0, stream>>>(ctx, feas, w, b0, out);
}

// Round 3
// 199.590 us; speedup vs baseline: 1.0206x; 1.0206x over previous
//
#include <hip/hip_runtime.h>

// Problem constants (fixed by setup_inputs)
#define Bdim 32
#define Ndim 64
#define Tdim 40
#define Adim 6
#define Zdim 64
#define Cdim 3
#define BNT   (Bdim * Ndim * Tdim)     // 81920 triples
#define ROWS  (BNT * Adim)             // 491520 rows of 64 floats
#define ROWS_PER_BLOCK 12              // = 2 triples; 240 % 12 == 0 -> no (b,n) straddle
#define NBLOCKS (ROWS / ROWS_PER_BLOCK) // 40960

// logits[b,n,t,a] = dot(df[b,n,t,a,:], z[b,n,:]) + u[b,n,t,a] - feas_mean_a(u)
// The frenet/projection term is constant over (t,a) and cancels exactly in
// (u - u_mean), so map_polylines/idx/pts are dead inputs.

template <int CTRL>
__device__ __forceinline__ float dpp_shr_add(float v) {
    int s = __builtin_amdgcn_update_dpp(0, __float_as_int(v), CTRL, 0xF, 0xF, true);
    return v + __int_as_float(s);
}

// Block = 192 threads (3 waves), 12 contiguous rows (2 triples).
// Dot phase: wave w, lane group g=lane>>4 -> row w*4+g, cols 4*(lane&15)..+3.
// df float4 index = blockIdx*768 + w*256 + lane*4 (fully contiguous, 1KB/instr).
// Reduction: 4 VALU DPP row_shr adds; lane 15 of each 16-group -> LDS.
// Epilogue: wave 0, lanes 0..13 (two octets; a = lane&7, triple = lane>>3).
__global__ __launch_bounds__(192) void mpd_fused_kernel(
    const float* __restrict__ df,    // (B,N,T,A,Z)
    const float* __restrict__ z,     // (B,N,Z)
    const float* __restrict__ ctx,   // (B,N,T,A,C)
    const int*   __restrict__ feas,  // (B,N,T,A)
    const float* __restrict__ w,     // (C,)
    const float* __restrict__ b0,    // (1,)
    float*       __restrict__ out)   // (B,N,T,A)
{
    __shared__ float dotL[ROWS_PER_BLOCK];
    const int tid  = threadIdx.x;
    const int wv   = tid >> 6;   // 0..2
    const int lane = tid & 63;
    const size_t rowBase = (size_t)blockIdx.x * ROWS_PER_BLOCK;

    // ---- dot phase ----
    const float4 d4 = *reinterpret_cast<const float4*>(
        df + rowBase * Zdim + wv * 256 + lane * 4);
    const int bn = blockIdx.x / 20;  // 20 blocks per (b,n)
    const float4 z4 = *reinterpret_cast<const float4*>(
        z + bn * Zdim + (lane & 15) * 4);

    float p = d4.x * z4.x + d4.y * z4.y + d4.z * z4.z + d4.w * z4.w;
    p = dpp_shr_add<0x111>(p);  // row_shr:1
    p = dpp_shr_add<0x112>(p);  // row_shr:2
    p = dpp_shr_add<0x114>(p);  // row_shr:4
    p = dpp_shr_add<0x118>(p);  // row_shr:8 -> lane 15 of 16-group = row sum
    if ((lane & 15) == 15)
        dotL[wv * 4 + (lane >> 4)] = p;
    __syncthreads();

    // ---- epilogue: wave 0 only, two octets ----
    if (wv == 0 && lane < 16) {
        const int a    = lane & 7;
        const int tri  = lane >> 3;
        const bool act = (a < Adim);
        const int row  = tri * Adim + a;  // 0..11 when act

        float u = 0.0f, fv = 0.0f;
        if (act) {
            const float* cp = ctx + (rowBase + row) * Cdim;
            u  = cp[0] * w[0] + cp[1] * w[1] + cp[2] * w[2] + b0[0];
            fv = (feas[rowBase + row] != 0) ? 1.0f : 0.0f;
        }
        // Octet reduce: sum(u*fv), sum(fv), sum(u). Lanes with a>=6 contribute 0.
        float uf = u * fv, fs = fv, ua = u;
#pragma unroll
        for (int off = 4; off >= 1; off >>= 1) {
            uf += __shfl_xor(uf, off, 64);
            fs += __shfl_xor(fs, off, 64);
            ua += __shfl_xor(ua, off, 64);
        }
        // No feasible action -> all treated feasible (mean of all 6).
        const float mean = (fs > 0.5f) ? (uf / fs) : (ua / 6.0f);
        if (act)
            out[rowBase + row] = dotL[row] + (u - mean);
    }
}

extern "C" void kernel_launch(void* const* d_in, const int* in_sizes, int n_in,
                              void* d_out, int out_size, void* d_ws, size_t ws_size,
                              hipStream_t stream) {
    // Inputs: map_polylines(0), idx(1), pts(2), z(3), decision_features(4),
    //         ctx_features(5), feasible_actions(6), u_ctx_w(7), u_ctx_b(8)
    const float* z    = (const float*)d_in[3];
    const float* df   = (const float*)d_in[4];
    const float* ctx  = (const float*)d_in[5];
    const int*   feas = (const int*)  d_in[6];
    const float* w    = (const float*)d_in[7];
    const float* b0   = (const float*)d_in[8];
    float* out = (float*)d_out;

    mpd_fused_kernel<<<NBLOCKS, 192, 0, stream>>>(df, z, ctx, feas, w, b0, out);
}